// Round 6
// baseline (315.882 us; speedup 1.0000x reference)
//
#include <hip/hip_runtime.h>
#include <hip/hip_bf16.h>
#include <math.h>

#define Tn   8192
#define Hn   1024
#define En   8
#define DFFn 4096

typedef __attribute__((ext_vector_type(8))) short bf16x8;           // 8 bf16 = 4 VGPRs
typedef __attribute__((ext_vector_type(8))) unsigned short u16x8;   // 16 B
typedef __attribute__((ext_vector_type(4))) float f32x4;

static __device__ inline unsigned short f2bf(float f) {
    __hip_bfloat16 h = __float2bfloat16(f);
    return __builtin_bit_cast(unsigned short, h);
}

// ---------------- prep ----------------------------------------------------
// blocks [0,256):    W1 -> W1t bf16 128x128-tile transpose
// blocks [256,512):  W2 -> W2t
// blocks [512,1536): gate + top-2 softmax sum + x->bf16 cast.
// r6: gate results go to PER-BLOCK partials (pb_load/pb_cnt) -- no global
// atomics, no zero-init memset dispatch; gemm0's aux block reduces them.
__global__ __launch_bounds__(256) void prep(
    const float* __restrict__ W1, unsigned short* __restrict__ W1t,
    const float* __restrict__ W2, unsigned short* __restrict__ W2t,
    const float* __restrict__ x, const float* __restrict__ gW,
    const float* __restrict__ gb, unsigned short* __restrict__ xbf,
    float* __restrict__ tokw, float* __restrict__ pb_load,
    int* __restrict__ pb_cnt)
{
    __shared__ float smem[8 * 1024 + En];
    __shared__ int   s_cnt[En];
    const int tid = threadIdx.x;
    const int id  = blockIdx.x;

    if (id < 512) {  // ---- fat transpose+cast ----
        const float* src; unsigned short* dst; int SR, SC, tb;
        if (id < 256) { src = W1; dst = W1t; SR = Hn;   SC = DFFn; tb = id; }
        else          { src = W2; dst = W2t; SR = DFFn; SC = Hn;   tb = id - 256; }
        const int tcs = SC >> 7;
        const int tr  = tb / tcs, tc = tb - tr * tcs;
        const int r0  = tr << 7, c0 = tc << 7;
        unsigned short* tile = (unsigned short*)smem;   // [128][128] swizzled

        #pragma unroll
        for (int i = 0; i < 16; ++i) {
            int idx = tid + i * 256;
            int r = idx >> 5, c4 = (idx & 31) << 2;
            float4 v = *(const float4*)(src + (size_t)(r0 + r) * SC + c0 + c4);
            int cs = c4 ^ (((r >> 3) & 7) << 2);
            ushort4 pk;
            pk.x = f2bf(v.x); pk.y = f2bf(v.y);
            pk.z = f2bf(v.z); pk.w = f2bf(v.w);
            *(ushort4*)(tile + r * 128 + cs) = pk;
        }
        __syncthreads();
        #pragma unroll
        for (int i = 0; i < 8; ++i) {
            int idx = tid + i * 256;
            int n = idx >> 4, kg = idx & 15, k0 = kg << 3;
            int s = (kg & 7) << 2;
            u16x8 o;
            #pragma unroll
            for (int j = 0; j < 8; ++j)
                o[j] = tile[(k0 + j) * 128 + (n ^ s)];
            *(u16x8*)(dst + (size_t)(c0 + n) * SR + r0 + k0) = o;
        }
        return;
    }

    // ---- gate + x cast ----
    const int gid = id - 512;                      // 0..1023
    float* gwt    = smem;
    float* s_load = smem + 8 * 1024;
    if (tid < En) { s_load[tid] = 0.f; s_cnt[tid] = 0; }
    #pragma unroll
    for (int i = 0; i < 32; ++i) {
        int f = tid + i * 256;
        gwt[(f & 7) * 1024 + (f >> 3)] = gW[f];
    }
    __syncthreads();

    const int lane = tid & 63;
    const int wv   = tid >> 6;

    for (int tok = gid * 4 + wv; tok < Tn; tok += 4096) {
        const float4* xr = (const float4*)(x + (size_t)tok * Hn);
        float acc[8] = {0.f,0.f,0.f,0.f,0.f,0.f,0.f,0.f};
        #pragma unroll
        for (int j = 0; j < Hn / 256; ++j) {
            int h4 = j * 64 + lane;
            float4 xv = xr[h4];
            ushort4 pk;
            pk.x = f2bf(xv.x); pk.y = f2bf(xv.y);
            pk.z = f2bf(xv.z); pk.w = f2bf(xv.w);
            ((ushort4*)xbf)[(size_t)tok * (Hn / 4) + h4] = pk;
            #pragma unroll
            for (int e = 0; e < 8; ++e) {
                const float4 w = *(const float4*)(gwt + e * 1024 + h4 * 4);
                acc[e] += xv.x * w.x + xv.y * w.y + xv.z * w.z + xv.w * w.w;
            }
        }
        #pragma unroll
        for (int e = 0; e < 8; ++e) {
            float v = acc[e];
            #pragma unroll
            for (int off = 32; off > 0; off >>= 1) v += __shfl_xor(v, off, 64);
            acc[e] = v + gb[e];
        }
        if (lane == 0) {
            #pragma unroll
            for (int e = 0; e < 8; ++e) atomicAdd(&s_load[e], acc[e]);
            int i1 = 0; float v1 = acc[0];
            #pragma unroll
            for (int e = 1; e < 8; ++e) if (acc[e] > v1) { v1 = acc[e]; i1 = e; }
            int i2 = -1; float v2 = -3.0e38f;
            #pragma unroll
            for (int e = 0; e < 8; ++e) if (e != i1 && acc[e] > v2) { v2 = acc[e]; i2 = e; }
            atomicAdd(&s_cnt[i1], 1);
            atomicAdd(&s_cnt[i2], 1);
            float e2 = __expf(v2 - v1);
            float t  = 1.0f + e2;
            tokw[tok] = 1.0f / t + e2 / t;
        }
    }
    __syncthreads();
    if (tid < En) {
        pb_load[gid * En + tid] = s_load[tid];   // plain stores, no atomics
        pb_cnt [gid * En + tid] = s_cnt[tid];
    }
}

// =================== one-phase-ahead pipelined 256-wide GEMM ==============
// C = epilogue(A @ Bt^T + bias); A:[M][K] bf16 row-major, Bt:[N][K] bf16.
// BM=256, BK=64, 512 thr = 8 waves. Double-buffered LDS, global_load_lds
// width-16, XOR slot-swizzle (conflict-free, verified r1).
//
// r6 G0: TRUE cross-phase pipeline. 6 register banks: afX/afY (A halves),
// bPa/bQa/bPb/bQb (B pairs x buffer parity). Phase p issues ONLY phase
// p+1's reads (4 or 8), then WAITL(count-just-issued) -> MFMA(p) executes
// while reads(p+1) drain in the LDS pipe. ONE barrier per phase.
//   MFMA map: P0(X,Pa) P1(X,Qa) P2(Y,Pa) P3(Y,Qa) P4(X,Pb) P5(X,Qb)
//             P6(Y,Pb) P7(Y,Qb)   [buf0: P0-3 tile 2i, buf1: P4-7 tile 2i+1]
//   read map: pre{X(b0h0),Pa(b0)}; P0:Qa(b0) P1:Y(b0h1) P2:Pb(b1) P3:X(b1h0)
//             P4:Qb(b1) P5:Y(b1h1) P6:Pa(b0,c2) P7:X(b0h0,c2)
//   stage map (2 loads each, as r1): P0:A13(b1,t1) P1:A02(b0,c2) P2:B01(b0)
//             P3:B23(b0) P4:A13(b0) P5:A02(b1,c3) P6:B01(b1) P7:B23(b1)
//   Hazard audit (stage(p) vs reads issued @p and @p-1): every pair is a
//   different buffer or disjoint 64-row units (e.g. P1 stages A units {0,2}
//   while P1 reads af-h1 = units {1,3}; P5 same on buf1). Reads older than
//   p-1 are drained by WAITL at p-1, which precedes SBAR(p-1) < stage(p).
//   vmcnt: VMC(4) at ends of P1,P3,P5,P7. FIFO (2 loads/phase): at P1-end
//   in-flight {P6',P7',P0,P1}=8 -> drains P6',P7' (b1,c3' stages; read @P2/
//   P4). P3-end drains P0(A13 b1; read@P5),P1(A02 c2; read@P7). P5-end
//   drains P2(B01 c2; read@P6),P3(B23 c2; read@P0'). P7-end drains
//   P4(A13 c2; read@P1'),P5(A02 b1 c3; read@P3'). Never below 4. First
//   iter: P1-end in-flight 6(prologue b1)+4 -> VMC(4) drains prologue b1
//   before its P2-P5 readers. Clamped tail re-stages same tile -> benign.
// r6 G1: r5 structure, WAITL(0)->WAITL(4) at P0/P2 (the r5 bug: WAITL(0)
//   drained the just-issued next-phase reads, cancelling the pipeline).
static __device__ inline bf16x8 ldsfrag(const char* base, int row, int chunk) {
    return *(const bf16x8*)(base + row * 128 + (((chunk) ^ (row & 7)) << 4));
}

template<int BN, int WM, int WN, int EPI>
__global__ __launch_bounds__(512, 2) void gemm8(
    const __hip_bfloat16* __restrict__ A,
    const __hip_bfloat16* __restrict__ Bt,
    const float* __restrict__ bias,
    const float* __restrict__ tokw,
    void* __restrict__ C, int N, int K, int nx,
    const float* __restrict__ pb_load, const int* __restrict__ pb_cnt,
    float* __restrict__ out_tail, int nblk)
{
    constexpr int BM = 256;
    constexpr int MR = (BM / WM) / 16;        // 8 (G0) or 4 (G1)
    constexpr int NR = (BN / WN) / 16;        // 4
    constexpr int AU = BM / 64;
    constexpr int BU = BN / 64;
    constexpr int ABYTES = BM * 64 * 2;       // 32 KB
    constexpr int BBYTES = BN * 64 * 2;       // 32/16 KB
    constexpr int TILEB  = ABYTES + BBYTES;

    extern __shared__ char lds[];

    const int tid = threadIdx.x;
    const int id  = blockIdx.x;

    if (EPI == 0 && id >= nblk) {   // ---- aux block: reduce gate partials ----
        float* sl = (float*)lds;
        int*   sc = (int*)(lds + 64);
        if (tid < En) { sl[tid] = 0.f; sc[tid] = 0; }
        __syncthreads();
        const int e = tid & 7;
        float p = 0.f; int c = 0;
        for (int g = tid >> 3; g < 1024; g += 64) {
            p += pb_load[g * En + e];
            c += pb_cnt [g * En + e];
        }
        atomicAdd(&sl[e], p);
        atomicAdd(&sc[e], c);
        __syncthreads();
        if (tid == 0) {
            float aux = 0.f;
            #pragma unroll
            for (int e2 = 0; e2 < En; ++e2) {
                float m = sl[e2] * (1.0f / (float)Tn);
                aux += m * m;
            }
            out_tail[0] = aux;
            #pragma unroll
            for (int e2 = 0; e2 < En; ++e2) out_tail[1 + e2] = (float)sc[e2];
        }
        return;
    }

    // bijective XCD swizzle (nblk % 8 == 0)
    int wg = id;
    { int xcd = wg & 7, idx = wg >> 3; wg = xcd * (nblk >> 3) + idx; }
    const int by = wg / nx, bx = wg % nx;
    const int m0 = by * BM, n0 = bx * BN;

    const int lane = tid & 63;
    const int wid  = tid >> 6;
    const int wn   = wid % WN;
    const int wm   = wid / WN;
    const int wrow = wm * (BM / WM);
    const int wcol = wn * (BN / WN);
    const int fr   = lane & 15;
    const int fq   = lane >> 4;

    const int sr = tid >> 3;
    const int sc = (tid & 7) ^ (sr & 7);
    unsigned aOff[AU], bOff[BU];
    #pragma unroll
    for (int u = 0; u < AU; ++u)
        aOff[u] = (unsigned)((m0 + u * 64 + sr) * K + sc * 8);
    #pragma unroll
    for (int u = 0; u < BU; ++u)
        bOff[u] = (unsigned)((n0 + u * 64 + sr) * K + sc * 8);

#define STA(b, u, kt) __builtin_amdgcn_global_load_lds( \
    (const __attribute__((address_space(1))) void*)(A + aOff[u] + (unsigned)(kt) * 64u), \
    (__attribute__((address_space(3))) void*)(lds + (b) * TILEB + (u) * 8192 + tid * 16), 16, 0, 0)
#define STB(b, u, kt) __builtin_amdgcn_global_load_lds( \
    (const __attribute__((address_space(1))) void*)(Bt + bOff[u] + (unsigned)(kt) * 64u), \
    (__attribute__((address_space(3))) void*)(lds + (b) * TILEB + ABYTES + (u) * 8192 + tid * 16), 16, 0, 0)

#define SBAR do { \
    __builtin_amdgcn_sched_barrier(0); \
    __builtin_amdgcn_s_barrier(); \
    __builtin_amdgcn_sched_barrier(0); } while (0)
#define WAITL(n) do { \
    asm volatile("s_waitcnt lgkmcnt(" #n ")" ::: "memory"); \
    __builtin_amdgcn_sched_barrier(0); } while (0)
#define VMC(n) do { asm volatile("s_waitcnt vmcnt(" #n ")" ::: "memory"); \
    __builtin_amdgcn_sched_barrier(0); } while (0)
#define PRIO1 __builtin_amdgcn_s_setprio(1)
#define PRIO0 __builtin_amdgcn_s_setprio(0)

    const int KT = K >> 6;

    if constexpr (WM == 2) {
        // ================= G0: 8-phase, one-phase-ahead rotation ==========
        bf16x8 afX[4][2], afY[4][2];          // A halves (h0 / h1)
        bf16x8 bPa[2][2], bQa[2][2];          // B pairs, buf0 parity
        bf16x8 bPb[2][2], bQb[2][2];          // B pairs, buf1 parity
        f32x4  acc[8][4];
        const f32x4 zero = {0.f, 0.f, 0.f, 0.f};
        #pragma unroll
        for (int i = 0; i < 8; ++i)
            #pragma unroll
            for (int j = 0; j < 4; ++j) acc[i][j] = zero;

#define RDAF(dst, b, half) do { _Pragma("unroll") \
    for (int m_ = 0; m_ < 4; ++m_) { _Pragma("unroll") \
        for (int ks_ = 0; ks_ < 2; ++ks_) \
            dst[m_][ks_] = ldsfrag(lds + (b) * TILEB, \
                wrow + ((half) * 4 + m_) * 16 + fr, ks_ * 4 + fq); } } while (0)
#define RDBF(dst, b, pr) do { _Pragma("unroll") \
    for (int n_ = 0; n_ < 2; ++n_) { _Pragma("unroll") \
        for (int ks_ = 0; ks_ < 2; ++ks_) \
            dst[n_][ks_] = ldsfrag(lds + (b) * TILEB + ABYTES, \
                wcol + ((pr) * 2 + n_) * 16 + fr, ks_ * 4 + fq); } } while (0)
#define MFMAQ(afb, bfb, hm, hn) do { \
    PRIO1; \
    _Pragma("unroll") \
    for (int m_ = 0; m_ < 4; ++m_) { _Pragma("unroll") \
        for (int n_ = 0; n_ < 2; ++n_) { _Pragma("unroll") \
            for (int ks_ = 0; ks_ < 2; ++ks_) \
                acc[(hm) * 4 + m_][(hn) * 2 + n_] = \
                    __builtin_amdgcn_mfma_f32_16x16x32_bf16( \
                        afb[m_][ks_], bfb[n_][ks_], \
                        acc[(hm) * 4 + m_][(hn) * 2 + n_], 0, 0, 0); } } \
    PRIO0; } while (0)

        // prologue: buf0 full (8) + buf1 minus A{1,3} (6)
        STA(0,0,0); STA(0,1,0); STA(0,2,0); STA(0,3,0);
        STB(0,0,0); STB(0,1,0); STB(0,2,0); STB(0,3,0);
        STA(1,0,1); STA(1,2,1);
        STB(1,0,1); STB(1,1,1); STB(1,2,1); STB(1,3,1);
        VMC(6);
        __builtin_amdgcn_s_barrier();
        __builtin_amdgcn_sched_barrier(0);
        RDAF(afX, 0, 0); RDBF(bPa, 0, 0);     // pre-reads for P0 (12)

        for (int i = 0; i < (KT >> 1); ++i) {
            const int t1 = 2 * i + 1;
            const int c2 = (2 * i + 2 < KT) ? 2 * i + 2 : KT - 1;
            const int c3 = (2 * i + 3 < KT) ? 2 * i + 3 : KT - 1;

            // P0: MFMA(X,Pa)=Q00(b0); reads Qa(b0); stage A13(b1,t1)
            RDBF(bQa, 0, 1);
            STA(1,1,t1); STA(1,3,t1);
            WAITL(4); MFMAQ(afX, bPa, 0, 0); SBAR;
            // P1: MFMA(X,Qa)=Q01; reads Y(b0,h1); stage A02(b0,c2); drain
            RDAF(afY, 0, 1);
            STA(0,0,c2); STA(0,2,c2);
            WAITL(8); MFMAQ(afX, bQa, 0, 1); VMC(4); SBAR;
            // P2: MFMA(Y,Pa)=Q10; reads Pb(b1); stage B01(b0,c2)
            RDBF(bPb, 1, 0);
            STB(0,0,c2); STB(0,1,c2);
            WAITL(4); MFMAQ(afY, bPa, 1, 0); SBAR;
            // P3: MFMA(Y,Qa)=Q11; reads X(b1,h0); stage B23(b0,c2); drain
            RDAF(afX, 1, 0);
            STB(0,2,c2); STB(0,3,c2);
            WAITL(8); MFMAQ(afY, bQa, 1, 1); VMC(4); SBAR;
            // P4: MFMA(X,Pb)=Q00(b1); reads Qb(b1); stage A13(b0,c2)
            RDBF(bQb, 1, 1);
            STA(0,1,c2); STA(0,3,c2);
            WAITL(4); MFMAQ(afX, bPb, 0, 0); SBAR;
            // P5: MFMA(X,Qb)=Q01; reads Y(b1,h1); stage A02(b1,c3); drain
            RDAF(afY, 1, 1);
            STA(1,0,c3); STA(1,2,c3);
            WAITL(8); MFMAQ(afX, bQb, 0, 1); VMC(4); SBAR;
            // P6: MFMA(Y,Pb)=Q10; reads Pa(b0,c2); stage B01(b1,c3)
            RDBF(bPa, 0, 0);
            STB(1,0,c3); STB(1,1,c3);
            WAITL(4); MFMAQ(afY, bPb, 1, 0); SBAR;
            // P7: MFMA(Y,Qb)=Q11; reads X(b0,c2,h0); stage B23(b1,c3); drain
            RDAF(afX, 0, 0);
            STB(1,2,c3); STB(1,3,c3);
            WAITL(8); MFMAQ(afY, bQb, 1, 1); VMC(4); SBAR;
        }

        // epilogue: C/D layout col = lane&15, row = (lane>>4)*4 + reg
        float bias4[4];
        #pragma unroll
        for (int ni = 0; ni < 4; ++ni)
            bias4[ni] = bias[n0 + wcol + ni * 16 + fr];
        #pragma unroll
        for (int mi = 0; mi < 8; ++mi) {
            #pragma unroll
            for (int ni = 0; ni < 4; ++ni) {
                const int col = n0 + wcol + ni * 16 + fr;
                const int rb  = m0 + wrow + mi * 16 + fq * 4;
                #pragma unroll
                for (int i2 = 0; i2 < 4; ++i2) {
                    float u  = acc[mi][ni][i2] + bias4[ni];
                    float uu = u * u;
                    float z  = u * __fmaf_rn(uu, -0.07135607f, -1.59576912f);
                    float e  = __expf(z);
                    float g  = u * __builtin_amdgcn_rcpf(1.0f + e);
                    ((__hip_bfloat16*)C)[(size_t)(rb + i2) * N + col] =
                        __float2bfloat16(g);
                }
            }
        }
#undef RDAF
#undef RDBF
#undef MFMAQ
    } else {
        // ================= G1: 4-phase pipeline (r5 + WAITL fix) ==========
        bf16x8 afh0[2][2], afh1[2][2];
        bf16x8 bfrS0[4][2], bfrS1[4][2];
        f32x4  acc[4][4];
        const f32x4 zero = {0.f, 0.f, 0.f, 0.f};
        #pragma unroll
        for (int i = 0; i < 4; ++i)
            #pragma unroll
            for (int j = 0; j < 4; ++j) acc[i][j] = zero;

#define RD_AH(dst, b, half) do { _Pragma("unroll") \
    for (int m_ = 0; m_ < 2; ++m_) { _Pragma("unroll") \
        for (int ks_ = 0; ks_ < 2; ++ks_) \
            dst[m_][ks_] = ldsfrag(lds + (b) * TILEB, \
                wrow + ((half) * 2 + m_) * 16 + fr, ks_ * 4 + fq); } } while (0)
#define RD_BS(dst, b) do { _Pragma("unroll") \
    for (int n_ = 0; n_ < 4; ++n_) { _Pragma("unroll") \
        for (int ks_ = 0; ks_ < 2; ++ks_) \
            dst[n_][ks_] = ldsfrag(lds + (b) * TILEB + ABYTES, \
                wcol + n_ * 16 + fr, ks_ * 4 + fq); } } while (0)
#define MFMAH(afx, bfx, hm) do { \
    PRIO1; \
    _Pragma("unroll") \
    for (int m_ = 0; m_ < 2; ++m_) { _Pragma("unroll") \
        for (int n_ = 0; n_ < 4; ++n_) { _Pragma("unroll") \
            for (int ks_ = 0; ks_ < 2; ++ks_) \
                acc[(hm) * 2 + m_][n_] = \
                    __builtin_amdgcn_mfma_f32_16x16x32_bf16( \
                        bfx[n_][ks_], afx[m_][ks_], \
                        acc[(hm) * 2 + m_][n_], 0, 0, 0); } } \
    PRIO0; } while (0)

        STA(0,0,0); STA(0,1,0); STA(0,2,0); STA(0,3,0);
        STB(0,0,0); STB(0,1,0);
        STB(1,0,1); STB(1,1,1);
        STA(1,0,1); STA(1,1,1); STA(1,2,1); STA(1,3,1);
        VMC(6);
        __builtin_amdgcn_s_barrier();
        __builtin_amdgcn_sched_barrier(0);
        RD_AH(afh0, 0, 0); RD_BS(bfrS0, 0);

        for (int i = 0; i < (KT >> 1); ++i) {
            const int c2 = (2 * i + 2 < KT) ? 2 * i + 2 : KT - 1;
            const int c3 = (2 * i + 3 < KT) ? 2 * i + 3 : KT - 1;

            // P0: MFMA h0(buf0) on 12 reads from P3-prev; issue afh1 (4)
            RD_AH(afh1, 0, 1);
            SBAR; WAITL(4); MFMAH(afh0, bfrS0, 0); VMC(0); SBAR;
            // P1: MFMA h1(buf0); issue 12 (buf1); stage buf0<-c2
            RD_AH(afh0, 1, 0); RD_BS(bfrS1, 1);
            STB(0,0,c2); STB(0,1,c2);
            STA(0,0,c2); STA(0,1,c2); STA(0,2,c2); STA(0,3,c2);
            SBAR; WAITL(12); MFMAH(afh1, bfrS0, 1); SBAR;
            // P2: MFMA h0(buf1); issue afh1' (4)
            RD_AH(afh1, 1, 1);
            SBAR; WAITL(4); MFMAH(afh0, bfrS1, 0); VMC(0); SBAR;
            // P3: MFMA h1(buf1); issue 12 (buf0=c2); stage buf1<-c3
            RD_AH(afh0, 0, 0); RD_BS(bfrS0, 0);
            STB(1,0,c3); STB(1,1,c3);
            STA(1,0,c3); STA(1,1,c3); STA(1,2,c3); STA(1,3,c3);
            SBAR; WAITL(12); MFMAH(afh1, bfrS1, 1); SBAR;
        }

        // epilogue (swapped D): M = lane&15, N = (lane>>4)*4+reg -> float4
        const int mrow0 = m0 + wrow + fr;
        const int ncol0 = n0 + wcol + fq * 4;
        float4 b4[4];
        #pragma unroll
        for (int ni = 0; ni < 4; ++ni)
            b4[ni] = *(const float4*)(bias + ncol0 + ni * 16);

        #pragma unroll
        for (int mi = 0; mi < 4; ++mi) {
            const int row = mrow0 + mi * 16;
            const float tw = tokw[row];
            #pragma unroll
            for (int ni = 0; ni < 4; ++ni) {
                f32x4 v = acc[mi][ni];
                float4 o;
                o.x = (v[0] + b4[ni].x) * tw;
                o.y = (v[1] + b4[ni].y) * tw;
                o.z = (v[2] + b4[ni].z) * tw;
                o.w = (v[3] + b4[ni].w) * tw;
                *(float4*)((float*)C + (size_t)row * N + ncol0 + ni * 16) = o;
            }
        }
#undef RD_AH
#undef RD_BS
#undef MFMAH
    }

#undef STA
#undef STB
#undef SBAR
#undef WAITL
#undef VMC
#undef PRIO1
#undef PRIO0
}

extern "C" void kernel_launch(void* const* d_in, const int* in_sizes, int n_in,
                              void* d_out, int out_size, void* d_ws, size_t ws_size,
                              hipStream_t stream)
{
    const float* x  = (const float*)d_in[0];
    const float* gW = (const float*)d_in[1];
    const float* gb = (const float*)d_in[2];
    const float* W1 = (const float*)d_in[3];
    const float* b1 = (const float*)d_in[4];
    const float* W2 = (const float*)d_in[5];
    const float* b2 = (const float*)d_in[6];
    float* out = (float*)d_out;

    char* ws = (char*)d_ws;
    __hip_bfloat16* xbf = (__hip_bfloat16*)ws;  ws += (size_t)Tn * Hn * 2;
    __hip_bfloat16* W1t = (__hip_bfloat16*)ws;  ws += (size_t)Hn * DFFn * 2;
    __hip_bfloat16* W2t = (__hip_bfloat16*)ws;  ws += (size_t)Hn * DFFn * 2;
    __hip_bfloat16* hdd = (__hip_bfloat16*)ws;  ws += (size_t)Tn * DFFn * 2;
    float* tokw     = (float*)ws;               ws += (size_t)Tn * 4;
    float* pb_load  = (float*)ws;               ws += 1024 * En * 4;
    int*   pb_cnt   = (int*)ws;                 ws += 1024 * En * 4;

    static bool attr_done = false;
    if (!attr_done) {
        (void)hipFuncSetAttribute(
            reinterpret_cast<const void*>(&gemm8<256, 2, 4, 0>),
            hipFuncAttributeMaxDynamicSharedMemorySize, 131072);
        (void)hipFuncSetAttribute(
            reinterpret_cast<const void*>(&gemm8<128, 4, 2, 1>),
            hipFuncAttributeMaxDynamicSharedMemorySize, 98304);
        attr_done = true;
    }

    // no memset: gate partials are plain stores; aux block reduces them
    prep<<<1536, 256, 0, stream>>>(W1, (unsigned short*)W1t,
                                   W2, (unsigned short*)W2t,
                                   x, gW, gb, (unsigned short*)xbf,
                                   tokw, pb_load, pb_cnt);

    // hdd = gelu(x @ W1 + b1): M=8192, N=4096, K=1024; 32x16 = 512 tiles
    gemm8<256, 2, 4, 0><<<513, 512, 131072, stream>>>(
        xbf, W1t, b1, nullptr, hdd, DFFn, Hn, 16,
        pb_load, pb_cnt, out + (size_t)Tn * Hn, 512);

    // out = (hdd @ W2 + b2) * tokw: M=8192, N=1024, K=4096; 32x8 = 256 blocks
    gemm8<128, 4, 2, 1><<<256, 512, 98304, stream>>>(
        hdd, W2t, b2, tokw, out, Hn, DFFn, 8,
        nullptr, nullptr, nullptr, 256);
}

// Round 7
// 262.881 us; speedup vs baseline: 1.2016x; 1.2016x over previous
//
#include <hip/hip_runtime.h>
#include <hip/hip_bf16.h>
#include <math.h>

#define Tn   8192
#define Hn   1024
#define En   8
#define DFFn 4096

typedef __attribute__((ext_vector_type(8))) short bf16x8;           // 8 bf16 = 4 VGPRs
typedef __attribute__((ext_vector_type(8))) unsigned short u16x8;   // 16 B
typedef __attribute__((ext_vector_type(4))) float f32x4;

static __device__ inline unsigned short f2bf(float f) {
    __hip_bfloat16 h = __float2bfloat16(f);
    return __builtin_bit_cast(unsigned short, h);
}

// ---------------- prep ----------------------------------------------------
// blocks [0,256):    W1 -> W1t bf16 128x128-tile transpose (fat blocks)
// blocks [256,512):  W2 -> W2t
// blocks [512,768):  gate + top-2 softmax sum + x->bf16 cast.
// r7 gate: 256 blocks x 32 tokens (was 1024 x 8) -- amortizes the 32 KB gW
// LDS staging 4x; staging loads are float4 (8/thread, was 32 scalar).
// Gate results -> per-block partials (no atomics, no memset); gemm0's aux
// block reduces them.
__global__ __launch_bounds__(256) void prep(
    const float* __restrict__ W1, unsigned short* __restrict__ W1t,
    const float* __restrict__ W2, unsigned short* __restrict__ W2t,
    const float* __restrict__ x, const float* __restrict__ gW,
    const float* __restrict__ gb, unsigned short* __restrict__ xbf,
    float* __restrict__ tokw, float* __restrict__ pb_load,
    int* __restrict__ pb_cnt)
{
    __shared__ float smem[8 * 1024 + En];
    __shared__ int   s_cnt[En];
    const int tid = threadIdx.x;
    const int id  = blockIdx.x;

    if (id < 512) {  // ---- fat transpose+cast ----
        const float* src; unsigned short* dst; int SR, SC, tb;
        if (id < 256) { src = W1; dst = W1t; SR = Hn;   SC = DFFn; tb = id; }
        else          { src = W2; dst = W2t; SR = DFFn; SC = Hn;   tb = id - 256; }
        const int tcs = SC >> 7;
        const int tr  = tb / tcs, tc = tb - tr * tcs;
        const int r0  = tr << 7, c0 = tc << 7;
        unsigned short* tile = (unsigned short*)smem;   // [128][128] swizzled

        #pragma unroll
        for (int i = 0; i < 16; ++i) {
            int idx = tid + i * 256;
            int r = idx >> 5, c4 = (idx & 31) << 2;
            float4 v = *(const float4*)(src + (size_t)(r0 + r) * SC + c0 + c4);
            int cs = c4 ^ (((r >> 3) & 7) << 2);
            ushort4 pk;
            pk.x = f2bf(v.x); pk.y = f2bf(v.y);
            pk.z = f2bf(v.z); pk.w = f2bf(v.w);
            *(ushort4*)(tile + r * 128 + cs) = pk;
        }
        __syncthreads();
        #pragma unroll
        for (int i = 0; i < 8; ++i) {
            int idx = tid + i * 256;
            int n = idx >> 4, kg = idx & 15, k0 = kg << 3;
            int s = (kg & 7) << 2;
            u16x8 o;
            #pragma unroll
            for (int j = 0; j < 8; ++j)
                o[j] = tile[(k0 + j) * 128 + (n ^ s)];
            *(u16x8*)(dst + (size_t)(c0 + n) * SR + r0 + k0) = o;
        }
        return;
    }

    // ---- gate + x cast; 256 blocks x 32 tokens ----
    const int gid = id - 512;                      // 0..255
    float* gwt    = smem;
    float* s_load = smem + 8 * 1024;
    if (tid < En) { s_load[tid] = 0.f; s_cnt[tid] = 0; }
    #pragma unroll
    for (int i = 0; i < 8; ++i) {                  // 2048 float4, coalesced
        int f4 = tid + i * 256;
        float4 v = ((const float4*)gW)[f4];
        int f = f4 << 2;
        gwt[((f + 0) & 7) * 1024 + ((f + 0) >> 3)] = v.x;
        gwt[((f + 1) & 7) * 1024 + ((f + 1) >> 3)] = v.y;
        gwt[((f + 2) & 7) * 1024 + ((f + 2) >> 3)] = v.z;
        gwt[((f + 3) & 7) * 1024 + ((f + 3) >> 3)] = v.w;
    }
    __syncthreads();

    const int lane = tid & 63;
    const int wv   = tid >> 6;

    for (int tok = gid * 4 + wv; tok < Tn; tok += 1024) {   // 8 toks/wave
        const float4* xr = (const float4*)(x + (size_t)tok * Hn);
        float acc[8] = {0.f,0.f,0.f,0.f,0.f,0.f,0.f,0.f};
        #pragma unroll
        for (int j = 0; j < Hn / 256; ++j) {
            int h4 = j * 64 + lane;
            float4 xv = xr[h4];
            ushort4 pk;
            pk.x = f2bf(xv.x); pk.y = f2bf(xv.y);
            pk.z = f2bf(xv.z); pk.w = f2bf(xv.w);
            ((ushort4*)xbf)[(size_t)tok * (Hn / 4) + h4] = pk;
            #pragma unroll
            for (int e = 0; e < 8; ++e) {
                const float4 w = *(const float4*)(gwt + e * 1024 + h4 * 4);
                acc[e] += xv.x * w.x + xv.y * w.y + xv.z * w.z + xv.w * w.w;
            }
        }
        #pragma unroll
        for (int e = 0; e < 8; ++e) {
            float v = acc[e];
            #pragma unroll
            for (int off = 32; off > 0; off >>= 1) v += __shfl_xor(v, off, 64);
            acc[e] = v + gb[e];
        }
        if (lane == 0) {
            #pragma unroll
            for (int e = 0; e < 8; ++e) atomicAdd(&s_load[e], acc[e]);
            int i1 = 0; float v1 = acc[0];
            #pragma unroll
            for (int e = 1; e < 8; ++e) if (acc[e] > v1) { v1 = acc[e]; i1 = e; }
            int i2 = -1; float v2 = -3.0e38f;
            #pragma unroll
            for (int e = 0; e < 8; ++e) if (e != i1 && acc[e] > v2) { v2 = acc[e]; i2 = e; }
            atomicAdd(&s_cnt[i1], 1);
            atomicAdd(&s_cnt[i2], 1);
            float e2 = __expf(v2 - v1);
            float t  = 1.0f + e2;
            tokw[tok] = 1.0f / t + e2 / t;
        }
    }
    __syncthreads();
    if (tid < En) {
        pb_load[gid * En + tid] = s_load[tid];   // plain stores, no atomics
        pb_cnt [gid * En + tid] = s_cnt[tid];
    }
}

// =================== phase-scheduled 256-wide GEMM (r1/r4 best forms) =====
// C = epilogue(A @ Bt^T + bias); A:[M][K] bf16 row-major, Bt:[N][K] bf16.
// BM=256, BK=64, 512 thr = 8 waves. Double-buffered LDS, global_load_lds
// width-16 staging, counted vmcnt (never 0 in loop), XOR slot-swizzle on
// global source + ds_read addr (conflict-free, verified r1).
//
// r7: SCHEDULE ITERATION CLOSED. r6's deeper pipeline spilled to scratch
// (acc 128 + frags 128 live VGPR > budget; WRITE_SIZE +102MB = scratch).
// The 256^2/8-wave geometry pins acc at 128 VGPR/lane -> no headroom for
// cross-phase register prefetch. Best measured forms restored:
//   G0 = r1 exact (78.4 us): 8-phase, 2-barrier MIDSYNC, 16-MFMA quadrant,
//        unswapped, scalar epilogue, vmcnt(6)@P3/P7.
//   G1 = r4 form (<=81): 4-phase, in-phase lgkm ladder, swapped operands,
//        float4 epilogue, vmcnt(2)@P1/P3.
static __device__ inline bf16x8 ldsfrag(const char* base, int row, int chunk) {
    return *(const bf16x8*)(base + row * 128 + (((chunk) ^ (row & 7)) << 4));
}

template<int BN, int WM, int WN, int EPI>
__global__ __launch_bounds__(512, 2) void gemm8(
    const __hip_bfloat16* __restrict__ A,
    const __hip_bfloat16* __restrict__ Bt,
    const float* __restrict__ bias,
    const float* __restrict__ tokw,
    void* __restrict__ C, int N, int K, int nx,
    const float* __restrict__ pb_load, const int* __restrict__ pb_cnt,
    float* __restrict__ out_tail, int nblk)
{
    constexpr int BM = 256;
    constexpr int MR = (BM / WM) / 16;        // 8 (G0) or 4 (G1)
    constexpr int NR = (BN / WN) / 16;        // 4
    constexpr int AU = BM / 64;
    constexpr int BU = BN / 64;
    constexpr int ABYTES = BM * 64 * 2;       // 32 KB
    constexpr int BBYTES = BN * 64 * 2;       // 32/16 KB
    constexpr int TILEB  = ABYTES + BBYTES;

    extern __shared__ char lds[];

    const int tid = threadIdx.x;
    const int id  = blockIdx.x;

    if (EPI == 0 && id >= nblk) {   // ---- aux block: reduce gate partials ----
        float* sl = (float*)lds;
        int*   sc = (int*)(lds + 64);
        if (tid < En) { sl[tid] = 0.f; sc[tid] = 0; }
        __syncthreads();
        const int e = tid & 7;
        float p = 0.f; int c = 0;
        for (int g = tid >> 3; g < 256; g += 64) {
            p += pb_load[g * En + e];
            c += pb_cnt [g * En + e];
        }
        atomicAdd(&sl[e], p);
        atomicAdd(&sc[e], c);
        __syncthreads();
        if (tid == 0) {
            float aux = 0.f;
            #pragma unroll
            for (int e2 = 0; e2 < En; ++e2) {
                float m = sl[e2] * (1.0f / (float)Tn);
                aux += m * m;
            }
            out_tail[0] = aux;
            #pragma unroll
            for (int e2 = 0; e2 < En; ++e2) out_tail[1 + e2] = (float)sc[e2];
        }
        return;
    }

    // bijective XCD swizzle (nblk % 8 == 0)
    int wg = id;
    { int xcd = wg & 7, idx = wg >> 3; wg = xcd * (nblk >> 3) + idx; }
    const int by = wg / nx, bx = wg % nx;
    const int m0 = by * BM, n0 = bx * BN;

    const int lane = tid & 63;
    const int wid  = tid >> 6;
    const int wn   = wid % WN;
    const int wm   = wid / WN;
    const int wrow = wm * (BM / WM);
    const int wcol = wn * (BN / WN);
    const int fr   = lane & 15;
    const int fq   = lane >> 4;

    const int sr = tid >> 3;
    const int sc = (tid & 7) ^ (sr & 7);
    unsigned aOff[AU], bOff[BU];
    #pragma unroll
    for (int u = 0; u < AU; ++u)
        aOff[u] = (unsigned)((m0 + u * 64 + sr) * K + sc * 8);
    #pragma unroll
    for (int u = 0; u < BU; ++u)
        bOff[u] = (unsigned)((n0 + u * 64 + sr) * K + sc * 8);

#define STA(b, u, kt) __builtin_amdgcn_global_load_lds( \
    (const __attribute__((address_space(1))) void*)(A + aOff[u] + (unsigned)(kt) * 64u), \
    (__attribute__((address_space(3))) void*)(lds + (b) * TILEB + (u) * 8192 + tid * 16), 16, 0, 0)
#define STB(b, u, kt) __builtin_amdgcn_global_load_lds( \
    (const __attribute__((address_space(1))) void*)(Bt + bOff[u] + (unsigned)(kt) * 64u), \
    (__attribute__((address_space(3))) void*)(lds + (b) * TILEB + ABYTES + (u) * 8192 + tid * 16), 16, 0, 0)

    bf16x8 af[MR / 2][2];
    bf16x8 bfr[4][2];
    f32x4  acc[MR][NR];
    const f32x4 zero = {0.f, 0.f, 0.f, 0.f};
    #pragma unroll
    for (int i = 0; i < MR; ++i)
        #pragma unroll
        for (int j = 0; j < NR; ++j) acc[i][j] = zero;

#define RDA(b, half) do { _Pragma("unroll") \
    for (int m_ = 0; m_ < MR / 2; ++m_) { _Pragma("unroll") \
        for (int ks_ = 0; ks_ < 2; ++ks_) \
            af[m_][ks_] = ldsfrag(lds + (b) * TILEB, \
                wrow + ((half) * (MR / 2) + m_) * 16 + fr, ks_ * 4 + fq); } } while (0)

#define RDB(b, half) do { _Pragma("unroll") \
    for (int n_ = 0; n_ < 2; ++n_) { _Pragma("unroll") \
        for (int ks_ = 0; ks_ < 2; ++ks_) \
            bfr[(half) * 2 + n_][ks_] = ldsfrag(lds + (b) * TILEB + ABYTES, \
                wcol + ((half) * 2 + n_) * 16 + fr, ks_ * 4 + fq); } } while (0)

// G0: one (hm,hn) C-quadrant, 16 MFMA, unswapped (r1 form)
#define MFMAQ(hm, hn) do { \
    __builtin_amdgcn_s_setprio(1); \
    _Pragma("unroll") \
    for (int m_ = 0; m_ < MR / 2; ++m_) { _Pragma("unroll") \
        for (int n_ = 0; n_ < 2; ++n_) { _Pragma("unroll") \
            for (int ks_ = 0; ks_ < 2; ++ks_) \
                acc[(hm) * (MR / 2) + m_][(hn) * 2 + n_] = \
                    __builtin_amdgcn_mfma_f32_16x16x32_bf16( \
                        af[m_][ks_], bfr[(hn) * 2 + n_][ks_], \
                        acc[(hm) * (MR / 2) + m_][(hn) * 2 + n_], 0, 0, 0); } } \
    __builtin_amdgcn_s_setprio(0); } while (0)

// G1 slices (swapped operands, r4 form)
#define MFMA1_N(hm, nn) do { _Pragma("unroll") \
    for (int m_ = 0; m_ < MR / 2; ++m_) { _Pragma("unroll") \
        for (int ks_ = 0; ks_ < 2; ++ks_) \
            acc[(hm) * (MR / 2) + m_][nn] = \
                __builtin_amdgcn_mfma_f32_16x16x32_bf16( \
                    bfr[nn][ks_], af[m_][ks_], \
                    acc[(hm) * (MR / 2) + m_][nn], 0, 0, 0); } } while (0)
#define MFMA1_M(hm, m_) do { _Pragma("unroll") \
    for (int n_ = 0; n_ < NR; ++n_) { _Pragma("unroll") \
        for (int ks_ = 0; ks_ < 2; ++ks_) \
            acc[(hm) * (MR / 2) + (m_)][n_] = \
                __builtin_amdgcn_mfma_f32_16x16x32_bf16( \
                    bfr[n_][ks_], af[m_][ks_], \
                    acc[(hm) * (MR / 2) + (m_)][n_], 0, 0, 0); } } while (0)

// single-fragment reads for G1's ladder
#define RD_A1(b, half, m_) do { _Pragma("unroll") \
    for (int ks_ = 0; ks_ < 2; ++ks_) \
        af[m_][ks_] = ldsfrag(lds + (b) * TILEB, \
            wrow + ((half) * (MR / 2) + (m_)) * 16 + fr, ks_ * 4 + fq); } while (0)
#define RD_B1(b, nn) do { _Pragma("unroll") \
    for (int ks_ = 0; ks_ < 2; ++ks_) \
        bfr[nn][ks_] = ldsfrag(lds + (b) * TILEB + ABYTES, \
            wcol + (nn) * 16 + fr, ks_ * 4 + fq); } while (0)

#define MIDSYNC do { \
    __builtin_amdgcn_sched_barrier(0); \
    __builtin_amdgcn_s_barrier(); \
    asm volatile("s_waitcnt lgkmcnt(0)" ::: "memory"); \
    __builtin_amdgcn_sched_barrier(0); } while (0)

#define SBARR do { \
    __builtin_amdgcn_sched_barrier(0); \
    __builtin_amdgcn_s_barrier(); \
    __builtin_amdgcn_sched_barrier(0); } while (0)

#define WAITL(n) do { \
    asm volatile("s_waitcnt lgkmcnt(" #n ")" ::: "memory"); \
    __builtin_amdgcn_sched_barrier(0); } while (0)

#define DRAIN6 do { asm volatile("s_waitcnt vmcnt(6)" ::: "memory"); \
    __builtin_amdgcn_sched_barrier(0); } while (0)
#define DRAIN2 do { asm volatile("s_waitcnt vmcnt(2)" ::: "memory"); \
    __builtin_amdgcn_sched_barrier(0); } while (0)
#define PRIO1 __builtin_amdgcn_s_setprio(1)
#define PRIO0 __builtin_amdgcn_s_setprio(0)

    const int KT = K >> 6;

    if constexpr (WM == 2) {
        // ================= G0: r1 exact 8-phase =================
        STA(0,0,0); STA(0,1,0); STA(0,2,0); STA(0,3,0);
        STB(0,0,0); STB(0,1,0); STB(0,2,0); STB(0,3,0);
        STA(1,0,1); STA(1,2,1);
        STB(1,0,1); STB(1,1,1); STB(1,2,1); STB(1,3,1);
        DRAIN6;
        __builtin_amdgcn_s_barrier();
        __builtin_amdgcn_sched_barrier(0);

        for (int i = 0; i < (KT >> 1); ++i) {
            const int t1 = 2 * i + 1;
            const int c2 = (2 * i + 2 < KT) ? 2 * i + 2 : KT - 1;
            const int c3 = (2 * i + 3 < KT) ? 2 * i + 3 : KT - 1;

            // P0: tile 2i quadrant (0,0)
            RDA(0, 0); RDB(0, 0);
            STA(1,1,t1); STA(1,3,t1);
            MIDSYNC; MFMAQ(0, 0); SBARR;
            // P1: quadrant (0,1)
            RDB(0, 1);
            STA(0,0,c2); STA(0,2,c2);
            MIDSYNC; MFMAQ(0, 1); SBARR;
            // P2: quadrant (1,0)
            RDA(0, 1);
            STB(0,0,c2); STB(0,1,c2);
            MIDSYNC; MFMAQ(1, 0); SBARR;
            // P3: quadrant (1,1); drain -> tile 2i+1 fully in LDS
            STB(0,2,c2); STB(0,3,c2);
            MIDSYNC; MFMAQ(1, 1); DRAIN6; SBARR;
            // P4: tile 2i+1 quadrant (0,0)
            RDA(1, 0); RDB(1, 0);
            STA(0,1,c2); STA(0,3,c2);
            MIDSYNC; MFMAQ(0, 0); SBARR;
            // P5
            RDB(1, 1);
            STA(1,0,c3); STA(1,2,c3);
            MIDSYNC; MFMAQ(0, 1); SBARR;
            // P6
            RDA(1, 1);
            STB(1,0,c3); STB(1,1,c3);
            MIDSYNC; MFMAQ(1, 0); SBARR;
            // P7; drain -> tile 2i+2 fully in LDS
            STB(1,2,c3); STB(1,3,c3);
            MIDSYNC; MFMAQ(1, 1); DRAIN6; SBARR;
        }

        // epilogue: C/D layout col = lane&15, row = (lane>>4)*4 + reg
        float bias4[NR];
        #pragma unroll
        for (int ni = 0; ni < NR; ++ni)
            bias4[ni] = bias[n0 + wcol + ni * 16 + fr];
        #pragma unroll
        for (int mi = 0; mi < MR; ++mi) {
            #pragma unroll
            for (int ni = 0; ni < NR; ++ni) {
                const int col = n0 + wcol + ni * 16 + fr;
                const int rb  = m0 + wrow + mi * 16 + fq * 4;
                #pragma unroll
                for (int i2 = 0; i2 < 4; ++i2) {
                    float u  = acc[mi][ni][i2] + bias4[ni];
                    float uu = u * u;
                    float z  = u * __fmaf_rn(uu, -0.07135607f, -1.59576912f);
                    float e  = __expf(z);
                    float g  = u * __builtin_amdgcn_rcpf(1.0f + e);
                    ((__hip_bfloat16*)C)[(size_t)(rb + i2) * N + col] =
                        __float2bfloat16(g);
                }
            }
        }
    } else {
        // ================= G1: r4 4-phase ladder =================
        STA(0,0,0); STA(0,1,0); STA(0,2,0); STA(0,3,0);
        STB(0,0,0); STB(0,1,0);
        STB(1,0,1); STB(1,1,1);
        DRAIN2;
        __builtin_amdgcn_s_barrier();
        __builtin_amdgcn_sched_barrier(0);

        for (int i = 0; i < (KT >> 1); ++i) {
            const int t1 = 2 * i + 1;
            const int c2 = (2 * i + 2 < KT) ? 2 * i + 2 : KT - 1;
            const int c3 = (2 * i + 3 < KT) ? 2 * i + 3 : KT - 1;

            // P0: half0 of tile 2i; stage buf1.A (tile 2i+1)
            RD_A1(0,0,0); RD_A1(0,0,1);
            RD_B1(0,0); RD_B1(0,1); RD_B1(0,2); RD_B1(0,3);
            STA(1,0,t1); STA(1,1,t1); STA(1,2,t1); STA(1,3,t1);
            SBARR; PRIO1;
            WAITL(6); MFMA1_N(0,0);
            WAITL(4); MFMA1_N(0,1);
            WAITL(2); MFMA1_N(0,2);
            WAITL(0); MFMA1_N(0,3);
            PRIO0; SBARR;
            // P1: half1; stage buf0.B (tile 2i+2); drain(2)
            RD_A1(0,1,0); RD_A1(0,1,1);
            STB(0,0,c2); STB(0,1,c2);
            SBARR; PRIO1;
            WAITL(2); MFMA1_M(1,0);
            WAITL(0); MFMA1_M(1,1);
            PRIO0; DRAIN2; SBARR;
            // P2: half0 of tile 2i+1; stage buf0.A (tile 2i+2)
            RD_A1(1,0,0); RD_A1(1,0,1);
            RD_B1(1,0); RD_B1(1,1); RD_B1(1,2); RD_B1(1,3);
            STA(0,0,c2); STA(0,1,c2); STA(0,2,c2); STA(0,3,c2);
            SBARR; PRIO1;
            WAITL(6); MFMA1_N(0,0);
            WAITL(4); MFMA1_N(0,1);
            WAITL(2); MFMA1_N(0,2);
            WAITL(0); MFMA1_N(0,3);
            PRIO0; SBARR;
            // P3: half1; stage buf1.B (tile 2i+3); drain(2)
            RD_A1(1,1,0); RD_A1(1,1,1);
            STB(1,0,c3); STB(1,1,c3);
            SBARR; PRIO1;
            WAITL(2); MFMA1_M(1,0);
            WAITL(0); MFMA1_M(1,1);
            PRIO0; DRAIN2; SBARR;
        }

        // epilogue (swapped D): M = lane&15, N = (lane>>4)*4+reg -> float4
        const int mrow0 = m0 + wrow + fr;
        const int ncol0 = n0 + wcol + fq * 4;
        float4 b4[NR];
        #pragma unroll
        for (int ni = 0; ni < NR; ++ni)
            b4[ni] = *(const float4*)(bias + ncol0 + ni * 16);

        #pragma unroll
        for (int mi = 0; mi < MR; ++mi) {
            const int row = mrow0 + mi * 16;
            const float tw = tokw[row];
            #pragma unroll
            for (int ni = 0; ni < NR; ++ni) {
                f32x4 v = acc[mi][ni];
                float4 o;
                o.x = (v[0] + b4[ni].x) * tw;
                o.y = (v[1] + b4[ni].y) * tw;
                o.z = (v[2] + b4[ni].z) * tw;
                o.w = (v[3] + b4[ni].w) * tw;
                *(float4*)((float*)C + (size_t)row * N + ncol0 + ni * 16) = o;
            }
        }
    }

#undef STA
#undef STB
#undef RDA
#undef RDB
#undef RD_A1
#undef RD_B1
#undef MFMAQ
#undef MFMA1_N
#undef MFMA1_M
#undef MIDSYNC
#undef SBARR
#undef WAITL
#undef DRAIN6
#undef DRAIN2
#undef PRIO1
#undef PRIO0
}

extern "C" void kernel_launch(void* const* d_in, const int* in_sizes, int n_in,
                              void* d_out, int out_size, void* d_ws, size_t ws_size,
                              hipStream_t stream)
{
    const float* x  = (const float*)d_in[0];
    const float* gW = (const float*)d_in[1];
    const float* gb = (const float*)d_in[2];
    const float* W1 = (const float*)d_in[3];
    const float* b1 = (const float*)d_in[4];
    const float* W2 = (const float*)d_in[5];
    const float* b2 = (const float*)d_in[6];
    float* out = (float*)d_out;

    char* ws = (char*)d_ws;
    __hip_bfloat16* xbf = (__hip_bfloat16*)ws;  ws += (size_t)Tn * Hn * 2;
    __hip_bfloat16* W1t = (__hip_bfloat16*)ws;  ws += (size_t)Hn * DFFn * 2;
    __hip_bfloat16* W2t = (__hip_bfloat16*)ws;  ws += (size_t)Hn * DFFn * 2;
    __hip_bfloat16* hdd = (__hip_bfloat16*)ws;  ws += (size_t)Tn * DFFn * 2;
    float* tokw     = (float*)ws;               ws += (size_t)Tn * 4;
    float* pb_load  = (float*)ws;               ws += 256 * En * 4;
    int*   pb_cnt   = (int*)ws;                 ws += 256 * En * 4;

    static bool attr_done = false;
    if (!attr_done) {
        (void)hipFuncSetAttribute(
            reinterpret_cast<const void*>(&gemm8<256, 2, 4, 0>),
            hipFuncAttributeMaxDynamicSharedMemorySize, 131072);
        (void)hipFuncSetAttribute(
            reinterpret_cast<const void*>(&gemm8<128, 4, 2, 1>),
            hipFuncAttributeMaxDynamicSharedMemorySize, 98304);
        attr_done = true;
    }

    // 512 fat transpose blocks + 256 gate blocks (no memset needed)
    prep<<<768, 256, 0, stream>>>(W1, (unsigned short*)W1t,
                                  W2, (unsigned short*)W2t,
                                  x, gW, gb, (unsigned short*)xbf,
                                  tokw, pb_load, pb_cnt);

    // hdd = gelu(x @ W1 + b1): M=8192, N=4096, K=1024; 32x16 = 512 tiles
    gemm8<256, 2, 4, 0><<<513, 512, 131072, stream>>>(
        xbf, W1t, b1, nullptr, hdd, DFFn, Hn, 16,
        pb_load, pb_cnt, out + (size_t)Tn * Hn, 512);

    // out = (hdd @ W2 + b2) * tokw: M=8192, N=1024, K=4096; 32x8 = 256 blocks
    gemm8<128, 4, 2, 1><<<256, 512, 98304, stream>>>(
        hdd, W2t, b2, tokw, out, Hn, DFFn, 8,
        nullptr, nullptr, nullptr, 256);
}